// Round 1
// baseline (2296.332 us; speedup 1.0000x reference)
//
#include <hip/hip_runtime.h>
#include <hip/hip_bf16.h>

typedef unsigned int uint32;
typedef unsigned short ushort16;

#define B_ 128
#define T_ 128
#define N_ 128
#define M_ 256
#define NT 512

// ---------- helpers ----------
__device__ __forceinline__ float bflo(uint32 u) { return __uint_as_float(u << 16); }
__device__ __forceinline__ float bfhi(uint32 u) { return __uint_as_float(u & 0xffff0000u); }
__device__ __forceinline__ float bfu(ushort16 v) { return __uint_as_float(((uint32)v) << 16); }
__device__ __forceinline__ ushort16 f2bf(float f) {
    uint32 u = __float_as_uint(f);
    u = (u + 0x7fffu + ((u >> 16) & 1u)) >> 16;
    return (ushort16)u;
}
__device__ __forceinline__ uint32 pack_bf(float a, float b) {
    return (uint32)f2bf(a) | ((uint32)f2bf(b) << 16);
}
__device__ __forceinline__ float fast_tanh(float x) {
    x = fminf(fmaxf(x, -15.f), 15.f);
    float e = __expf(2.f * x);
    return __fdividef(e - 1.f, e + 1.f);
}
__device__ __forceinline__ float fast_sigmoid(float x) {
    return __fdividef(1.f, 1.f + __expf(-x));
}

// ---------- prep 1: transpose + bf16-convert weights ----------
// WeP  [jp<256][s<128]  : pair (We[s][2jp], We[s][2jp+1])
// WihT [n<128][kp<512]  : pair (W_ih[2kp][n], W_ih[2kp+1][n])
// WhhT [j<256][kp<512]  : pair (W_hh[2kp][j], W_hh[2kp+1][j])
__global__ void prep_weights(const float* __restrict__ We, const float* __restrict__ W_ih,
                             const float* __restrict__ W_hh, uint32* __restrict__ WeP,
                             uint32* __restrict__ WihT, uint32* __restrict__ WhhT) {
    int idx = blockIdx.x * 256 + threadIdx.x;
    if (idx < 32768) {
        int s = idx & 127, jp = idx >> 7;
        WeP[idx] = pack_bf(We[s * 512 + 2 * jp], We[s * 512 + 2 * jp + 1]);
    } else if (idx < 98304) {
        int i2 = idx - 32768;
        int kp = i2 & 511, n = i2 >> 9;
        WihT[i2] = pack_bf(W_ih[(2 * kp) * 128 + n], W_ih[(2 * kp + 1) * 128 + n]);
    } else if (idx < 229376) {
        int i3 = idx - 98304;
        int kp = i3 & 511, j = i3 >> 9;
        WhhT[i3] = pack_bf(W_hh[(2 * kp) * 256 + j], W_hh[(2 * kp + 1) * 256 + j]);
    }
}

// ---------- prep 2: Ux[b,s,n] = sum_t x[b,t,n] * Ue[s,t]  (bf16 out) ----------
__global__ void ux_kernel(const float* __restrict__ x, const float* __restrict__ Ue,
                          ushort16* __restrict__ Uxg) {
    int b = blockIdx.x >> 1, h = blockIdx.x & 1;
    int n = threadIdx.x & 127, sg = threadIdx.x >> 7;
    int s0 = h * 64 + sg * 16;
    float acc[16];
#pragma unroll
    for (int k = 0; k < 16; ++k) acc[k] = 0.f;
    for (int t0 = 0; t0 < 128; t0 += 16) {
        float xv[16];
#pragma unroll
        for (int tt = 0; tt < 16; ++tt) xv[tt] = x[(b * 128 + t0 + tt) * 128 + n];
#pragma unroll
        for (int k = 0; k < 16; ++k) {
            const float4* uep = (const float4*)(Ue + (s0 + k) * 128 + t0);
            float4 u0 = uep[0], u1 = uep[1], u2 = uep[2], u3 = uep[3];
            acc[k] += xv[0] * u0.x + xv[1] * u0.y + xv[2] * u0.z + xv[3] * u0.w
                    + xv[4] * u1.x + xv[5] * u1.y + xv[6] * u1.z + xv[7] * u1.w
                    + xv[8] * u2.x + xv[9] * u2.y + xv[10] * u2.z + xv[11] * u2.w
                    + xv[12] * u3.x + xv[13] * u3.y + xv[14] * u3.z + xv[15] * u3.w;
        }
    }
#pragma unroll
    for (int k = 0; k < 16; ++k)
        Uxg[b * 16384 + (s0 + k) * 128 + n] = f2bf(acc[k]);
}

// ---------- main: one persistent block per batch element ----------
__global__ __launch_bounds__(NT, 1)
void encoder_kernel(const float* __restrict__ x, const float* __restrict__ v_e,
                    const float* __restrict__ b_ih, const float* __restrict__ b_hh,
                    const ushort16* __restrict__ Uxg, const uint32* __restrict__ WeP,
                    const uint32* __restrict__ WihT, const uint32* __restrict__ WhhT,
                    float* __restrict__ out) {
    __shared__ __align__(16) ushort16 Ux_s[128 * 128];  // [s][n] bf16, 32KB
    __shared__ __align__(16) float hs_s[512];           // h:[0,256) c:[256,512)
    __shared__ __align__(16) float bias_s[1024];
    __shared__ float ve_s[128];
    __shared__ float xt_s[128];
    __shared__ float web_s[128];
    __shared__ __align__(16) float part_s[512];
    __shared__ float sc_s[128];
    __shared__ float xw_s[128];
    __shared__ float gates_s[1024];

    const int tid = threadIdx.x;
    const int b = blockIdx.x;

    {   // load this batch's Ux tile (coalesced uint4)
        const uint4* src = (const uint4*)(Uxg + b * 16384);
        uint4* dst = (uint4*)Ux_s;
        for (int i = tid; i < 2048; i += NT) dst[i] = src[i];
    }
    hs_s[tid] = 0.f;
    bias_s[tid] = b_ih[tid] + b_hh[tid];
    bias_s[tid + 512] = b_ih[tid + 512] + b_hh[tid + 512];
    if (tid < 128) ve_s[tid] = v_e[tid];
    __syncthreads();

    const int lane_s = tid & 127;   // s (ph1) / n (ph2)
    const int grp = tid >> 7;       // jg (ph1) / sg (ph2)

    for (int t = 0; t < 128; ++t) {
        // ---- phase 1: we_b[s] = [h|c] . We[s,:]  (bf16 weights, fp32 acc) ----
        if (tid < 128) xt_s[tid] = x[(b * 128 + t) * 128 + tid];
        {
            float acc = 0.f;
            const float2* hs2 = (const float2*)hs_s;
#pragma unroll 8
            for (int jp = grp * 64; jp < grp * 64 + 64; ++jp) {
                uint32 u = WeP[jp * 128 + lane_s];
                float2 hp = hs2[jp];
                acc += hp.x * bflo(u) + hp.y * bfhi(u);
            }
            part_s[grp * 128 + lane_s] = acc;
        }
        __syncthreads();
        if (tid < 128)
            web_s[tid] = part_s[tid] + part_s[128 + tid] + part_s[256 + tid] + part_s[384 + tid];
        __syncthreads();

        // ---- phase 2: scores[n] = sum_s ve[s] * tanh(we_b[s] + Ux[s,n]) ----
        {
            float acc = 0.f;
#pragma unroll 4
            for (int k = 0; k < 32; ++k) {
                int s = grp * 32 + k;
                float a = web_s[s] + bfu(Ux_s[s * 128 + lane_s]);
                acc += ve_s[s] * fast_tanh(a);
            }
            part_s[grp * 128 + lane_s] = acc;
        }
        __syncthreads();
        if (tid < 128)
            sc_s[tid] = part_s[tid] + part_s[128 + tid] + part_s[256 + tid] + part_s[384 + tid];
        __syncthreads();

        // ---- phase 3: softmax over n (single wave, no intra-phase barriers) ----
        if (tid < 64) {
            float v0 = sc_s[tid], v1 = sc_s[tid + 64];
            float m = fmaxf(v0, v1);
#pragma unroll
            for (int off = 32; off > 0; off >>= 1) m = fmaxf(m, __shfl_xor(m, off));
            float e0 = __expf(v0 - m), e1 = __expf(v1 - m);
            float ssum = e0 + e1;
#pragma unroll
            for (int off = 32; off > 0; off >>= 1) ssum += __shfl_xor(ssum, off);
            float inv = __fdividef(1.f, ssum);
            xw_s[tid] = xt_s[tid] * e0 * inv;
            xw_s[tid + 64] = xt_s[tid + 64] * e1 * inv;
        }
        __syncthreads();

        // ---- phase 4: gates[k] = xw.W_ih[k,:] + h.W_hh[k,:] + bias[k] ----
        {
            float2 bia = ((const float2*)bias_s)[tid];
            float acc0 = bia.x, acc1 = bia.y;
#pragma unroll 8
            for (int n = 0; n < 128; ++n) {
                uint32 u = WihT[n * 512 + tid];
                float xn = xw_s[n];
                acc0 += xn * bflo(u);
                acc1 += xn * bfhi(u);
            }
#pragma unroll 8
            for (int j = 0; j < 256; ++j) {
                uint32 u = WhhT[j * 512 + tid];
                float hj = hs_s[j];
                acc0 += hj * bflo(u);
                acc1 += hj * bfhi(u);
            }
            gates_s[2 * tid] = acc0;
            gates_s[2 * tid + 1] = acc1;
        }
        __syncthreads();

        // ---- phase 5: LSTM pointwise + store h ----
        if (tid < 256) {
            float ii = gates_s[tid], ff = gates_s[256 + tid];
            float gg = gates_s[512 + tid], oo = gates_s[768 + tid];
            float c = hs_s[256 + tid];
            float c2 = fast_sigmoid(ff) * c + fast_sigmoid(ii) * fast_tanh(gg);
            float h2 = fast_sigmoid(oo) * fast_tanh(c2);
            hs_s[256 + tid] = c2;
            hs_s[tid] = h2;
            out[(t * 128 + b) * 256 + tid] = h2;
        }
        __syncthreads();
    }
}

extern "C" void kernel_launch(void* const* d_in, const int* in_sizes, int n_in,
                              void* d_out, int out_size, void* d_ws, size_t ws_size,
                              hipStream_t stream) {
    const float* x    = (const float*)d_in[0];
    const float* We   = (const float*)d_in[1];
    const float* Ue   = (const float*)d_in[2];
    const float* v_e  = (const float*)d_in[3];
    const float* W_ih = (const float*)d_in[4];
    const float* W_hh = (const float*)d_in[5];
    const float* b_ih = (const float*)d_in[6];
    const float* b_hh = (const float*)d_in[7];
    float* out = (float*)d_out;

    char* w = (char*)d_ws;
    ushort16* Uxg = (ushort16*)w;                  // 128*128*128*2 = 4 MB
    uint32* WeP  = (uint32*)(w + 4194304);         // 128 KB
    uint32* WihT = (uint32*)(w + 4325376);         // 256 KB
    uint32* WhhT = (uint32*)(w + 4587520);         // 512 KB

    prep_weights<<<896, 256, 0, stream>>>(We, W_ih, W_hh, WeP, WihT, WhhT);
    ux_kernel<<<256, 512, 0, stream>>>(x, Ue, Uxg);
    encoder_kernel<<<128, NT, 0, stream>>>(x, v_e, b_ih, b_hh, Uxg, WeP, WihT, WhhT, out);
}

// Round 2
// 1786.691 us; speedup vs baseline: 1.2852x; 1.2852x over previous
//
#include <hip/hip_runtime.h>
#include <hip/hip_bf16.h>

typedef unsigned int uint32;
typedef unsigned short ushort16;

#define NT 1024

// ---------- helpers ----------
__device__ __forceinline__ float bflo(uint32 u) { return __uint_as_float(u << 16); }
__device__ __forceinline__ float bfhi(uint32 u) { return __uint_as_float(u & 0xffff0000u); }
__device__ __forceinline__ float bfu(ushort16 v) { return __uint_as_float(((uint32)v) << 16); }
__device__ __forceinline__ ushort16 f2bf(float f) {
    uint32 u = __float_as_uint(f);
    u = (u + 0x7fffu + ((u >> 16) & 1u)) >> 16;
    return (ushort16)u;
}
__device__ __forceinline__ uint32 pack_bf(float a, float b) {
    return (uint32)f2bf(a) | ((uint32)f2bf(b) << 16);
}
__device__ __forceinline__ float fast_tanh(float x) {
    x = fminf(fmaxf(x, -15.f), 15.f);
    float e = __expf(2.f * x);
    return __fdividef(e - 1.f, e + 1.f);
}
__device__ __forceinline__ float fast_sigmoid(float x) {
    return __fdividef(1.f, 1.f + __expf(-x));
}

// ---------- prep 1: bf16-convert + re-layout weights ----------
// WeQ: uint32[64*128*4]. Index (jq*128+s)*4+p -> pack(We[s][8jq+2p], We[s][8jq+2p+1])
//   (one uint4 per (jq,s): 8 consecutive hs-columns j=8jq..8jq+7 for score-row s)
// Wc : uint32[384*128*4]. Index (n*128+o)*4+p -> pack(W[8o+2p][n], W[8o+2p+1][n])
//   where W[k][n] = (n<128) ? W_ih[k][n] : W_hh[k][n-128]  (combined K-dim = [xw|h])
//   (one uint4 per (n,o): 8 consecutive gates k=8o..8o+7 at reduction column n)
__global__ void prep_weights(const float* __restrict__ We, const float* __restrict__ W_ih,
                             const float* __restrict__ W_hh, uint32* __restrict__ WeQ,
                             uint32* __restrict__ Wc) {
    int idx = blockIdx.x * 256 + threadIdx.x;
    if (idx < 32768) {
        int p = idx & 3, s = (idx >> 2) & 127, jq = idx >> 9;
        int j = 8 * jq + 2 * p;
        WeQ[idx] = pack_bf(We[s * 512 + j], We[s * 512 + j + 1]);
    } else if (idx < 229376) {
        int i2 = idx - 32768;
        int p = i2 & 3, o = (i2 >> 2) & 127, n = i2 >> 9;
        int k = 8 * o + 2 * p;
        float w0, w1;
        if (n < 128) {
            w0 = W_ih[k * 128 + n];
            w1 = W_ih[(k + 1) * 128 + n];
        } else {
            w0 = W_hh[k * 256 + (n - 128)];
            w1 = W_hh[(k + 1) * 256 + (n - 128)];
        }
        Wc[i2] = pack_bf(w0, w1);
    }
}

// ---------- prep 2: Ux[b,s,n] = sum_t x[b,t,n] * Ue[s,t]  (bf16 out) ----------
__global__ void ux_kernel(const float* __restrict__ x, const float* __restrict__ Ue,
                          ushort16* __restrict__ Uxg) {
    int b = blockIdx.x >> 1, h = blockIdx.x & 1;
    int n = threadIdx.x & 127, sg = threadIdx.x >> 7;
    int s0 = h * 64 + sg * 16;
    float acc[16];
#pragma unroll
    for (int k = 0; k < 16; ++k) acc[k] = 0.f;
    for (int t0 = 0; t0 < 128; t0 += 16) {
        float xv[16];
#pragma unroll
        for (int tt = 0; tt < 16; ++tt) xv[tt] = x[(b * 128 + t0 + tt) * 128 + n];
#pragma unroll
        for (int k = 0; k < 16; ++k) {
            const float4* uep = (const float4*)(Ue + (s0 + k) * 128 + t0);
            float4 u0 = uep[0], u1 = uep[1], u2 = uep[2], u3 = uep[3];
            acc[k] += xv[0] * u0.x + xv[1] * u0.y + xv[2] * u0.z + xv[3] * u0.w
                    + xv[4] * u1.x + xv[5] * u1.y + xv[6] * u1.z + xv[7] * u1.w
                    + xv[8] * u2.x + xv[9] * u2.y + xv[10] * u2.z + xv[11] * u2.w
                    + xv[12] * u3.x + xv[13] * u3.y + xv[14] * u3.z + xv[15] * u3.w;
        }
    }
#pragma unroll
    for (int k = 0; k < 16; ++k)
        Uxg[b * 16384 + (s0 + k) * 128 + n] = f2bf(acc[k]);
}

// ---------- main: one persistent 1024-thread block per batch element ----------
__global__ __launch_bounds__(NT, 1)
void encoder_kernel(const float* __restrict__ x, const float* __restrict__ v_e,
                    const float* __restrict__ b_ih, const float* __restrict__ b_hh,
                    const ushort16* __restrict__ Uxg, const uint4* __restrict__ WeQ4,
                    const uint4* __restrict__ Wc4, float* __restrict__ out) {
    __shared__ __align__(16) ushort16 Ux_s[128 * 128];  // [s][n] bf16, 32 KB
    __shared__ __align__(16) float part4[8192];         // gate partials, 32 KB
    __shared__ __align__(16) float hs_s[512];           // [h(256) | c(256)] for We
    __shared__ __align__(16) float v_s[384];            // [xw(128) | h(256)] for gates
    __shared__ __align__(16) float bias_s[1024];
    __shared__ float part1[1024];                       // ph1 partials
    __shared__ float part2[1024];                       // ph2 partials
    __shared__ float web_s[128];
    __shared__ float ve_s[128];
    __shared__ float xt_s[128];

    const int tid = threadIdx.x;
    const int b = blockIdx.x;
    const int lane = tid & 127;   // s (ph1) / n (ph2) / o (ph4)
    const int grp = tid >> 7;     // split-K group, 0..7

    {   // load this batch's Ux tile (coalesced uint4)
        const uint4* src = (const uint4*)(Uxg + b * 16384);
        uint4* dst = (uint4*)Ux_s;
        for (int i = tid; i < 2048; i += NT) dst[i] = src[i];
    }
    bias_s[tid] = b_ih[tid] + b_hh[tid];
    if (tid < 512) hs_s[tid] = 0.f;
    if (tid < 384) v_s[tid] = 0.f;
    if (tid < 128) ve_s[tid] = v_e[tid];
    __syncthreads();

    for (int t = 0; t < 128; ++t) {
        // x_t for softmax (consumed after B3; prev readers done before prev B4)
        if (tid < 128) xt_s[tid] = x[(b * 128 + t) * 128 + tid];

        // ---- ph4a: gate partials, h-part (needs only prev h, no barrier) ----
        // thread owns gate octet o = lane (gates 8o..8o+7), K-chunk grp
        float2 a0 = make_float2(0.f, 0.f), a1 = a0, a2 = a0, a3 = a0;
        {
#pragma unroll 8
            for (int i = 0; i < 32; ++i) {
                int n = 128 + grp * 32 + i;
                uint4 w = Wc4[n * 128 + lane];
                float vn = v_s[n];
                a0.x += vn * bflo(w.x); a0.y += vn * bfhi(w.x);
                a1.x += vn * bflo(w.y); a1.y += vn * bfhi(w.y);
                a2.x += vn * bflo(w.z); a2.y += vn * bfhi(w.z);
                a3.x += vn * bflo(w.w); a3.y += vn * bfhi(w.w);
            }
        }

        // ---- ph1: web[s] = [h|c] . We[s,:]  (split-K over 8 groups) ----
        {
            float acc = 0.f;
            const float2* hs2 = (const float2*)hs_s;
#pragma unroll
            for (int jq = grp * 8; jq < grp * 8 + 8; ++jq) {
                uint4 w = WeQ4[jq * 128 + lane];
                float2 h0 = hs2[jq * 4 + 0], h1 = hs2[jq * 4 + 1];
                float2 h2v = hs2[jq * 4 + 2], h3 = hs2[jq * 4 + 3];
                acc += h0.x * bflo(w.x) + h0.y * bfhi(w.x)
                     + h1.x * bflo(w.y) + h1.y * bfhi(w.y)
                     + h2v.x * bflo(w.z) + h2v.y * bfhi(w.z)
                     + h3.x * bflo(w.w) + h3.y * bfhi(w.w);
            }
            part1[grp * 128 + lane] = acc;
        }
        __syncthreads();  // B1
        if (tid < 128) {
            float w = 0.f;
#pragma unroll
            for (int g = 0; g < 8; ++g) w += part1[g * 128 + tid];
            web_s[tid] = w;
        }
        __syncthreads();  // B2

        // ---- ph2: scores[n] = sum_s ve[s] * tanh(web[s] + Ux[s,n]) ----
        {
            float acc = 0.f;
#pragma unroll 4
            for (int k = 0; k < 16; ++k) {
                int s = grp * 16 + k;
                float a = web_s[s] + bfu(Ux_s[s * 128 + lane]);
                acc += ve_s[s] * fast_tanh(a);
            }
            part2[grp * 128 + lane] = acc;
        }
        __syncthreads();  // B3

        // ---- ph3: reduce + softmax + xw, single wave ----
        if (tid < 64) {
            float v0 = 0.f, v1 = 0.f;
#pragma unroll
            for (int g = 0; g < 8; ++g) {
                v0 += part2[g * 128 + tid];
                v1 += part2[g * 128 + tid + 64];
            }
            float m = fmaxf(v0, v1);
#pragma unroll
            for (int off = 32; off > 0; off >>= 1) m = fmaxf(m, __shfl_xor(m, off));
            float e0 = __expf(v0 - m), e1 = __expf(v1 - m);
            float ssum = e0 + e1;
#pragma unroll
            for (int off = 32; off > 0; off >>= 1) ssum += __shfl_xor(ssum, off);
            float inv = __fdividef(1.f, ssum);
            v_s[tid] = xt_s[tid] * e0 * inv;
            v_s[tid + 64] = xt_s[tid + 64] * e1 * inv;
        }
        __syncthreads();  // B4

        // ---- ph4b: gate partials, xw-part; then dump partials ----
        {
#pragma unroll 8
            for (int i = 0; i < 16; ++i) {
                int n = grp * 16 + i;
                uint4 w = Wc4[n * 128 + lane];
                float vn = v_s[n];
                a0.x += vn * bflo(w.x); a0.y += vn * bfhi(w.x);
                a1.x += vn * bflo(w.y); a1.y += vn * bfhi(w.y);
                a2.x += vn * bflo(w.z); a2.y += vn * bfhi(w.z);
                a3.x += vn * bflo(w.w); a3.y += vn * bfhi(w.w);
            }
            float4* p4 = (float4*)&part4[grp * 1024 + 8 * lane];
            p4[0] = make_float4(a0.x, a0.y, a1.x, a1.y);
            p4[1] = make_float4(a2.x, a2.y, a3.x, a3.y);
        }
        __syncthreads();  // B5

        // ---- ph5: reduce gates + LSTM pointwise + store h ----
        if (tid < 256) {
            int j = tid;
            float gi = bias_s[j], gf = bias_s[256 + j];
            float gg = bias_s[512 + j], go = bias_s[768 + j];
#pragma unroll
            for (int g = 0; g < 8; ++g) {
                const float* pp = part4 + g * 1024;
                gi += pp[j]; gf += pp[256 + j]; gg += pp[512 + j]; go += pp[768 + j];
            }
            float c = hs_s[256 + j];
            float c2 = fast_sigmoid(gf) * c + fast_sigmoid(gi) * fast_tanh(gg);
            float h2 = fast_sigmoid(go) * fast_tanh(c2);
            hs_s[256 + j] = c2;
            hs_s[j] = h2;
            v_s[128 + j] = h2;
            out[(t * 128 + b) * 256 + j] = h2;
        }
        __syncthreads();  // B6
    }
}

extern "C" void kernel_launch(void* const* d_in, const int* in_sizes, int n_in,
                              void* d_out, int out_size, void* d_ws, size_t ws_size,
                              hipStream_t stream) {
    const float* x    = (const float*)d_in[0];
    const float* We   = (const float*)d_in[1];
    const float* Ue   = (const float*)d_in[2];
    const float* v_e  = (const float*)d_in[3];
    const float* W_ih = (const float*)d_in[4];
    const float* W_hh = (const float*)d_in[5];
    const float* b_ih = (const float*)d_in[6];
    const float* b_hh = (const float*)d_in[7];
    float* out = (float*)d_out;

    char* w = (char*)d_ws;
    ushort16* Uxg = (ushort16*)w;                  // 128*128*128*2 = 4 MB
    uint32* WeQ  = (uint32*)(w + 4194304);         // 64*128*4*4   = 128 KB
    uint32* Wc   = (uint32*)(w + 4325376);         // 384*128*4*4  = 768 KB

    prep_weights<<<896, 256, 0, stream>>>(We, W_ih, W_hh, WeQ, Wc);
    ux_kernel<<<256, 512, 0, stream>>>(x, Ue, Uxg);
    encoder_kernel<<<128, NT, 0, stream>>>(x, v_e, b_ih, b_hh, Uxg,
                                           (const uint4*)WeQ, (const uint4*)Wc, out);
}

// Round 4
// 1659.177 us; speedup vs baseline: 1.3840x; 1.0769x over previous
//
#include <hip/hip_runtime.h>
#include <hip/hip_bf16.h>
#include <hip/hip_fp16.h>

typedef unsigned int uint32;
typedef _Float16 hf2 __attribute__((ext_vector_type(2)));

#define NT 1024

// ---------- helpers ----------
__device__ __forceinline__ float bfu(unsigned short v) { return __uint_as_float(((uint32)v) << 16); }
__device__ __forceinline__ unsigned short f2bf(float f) {
    uint32 u = __float_as_uint(f);
    u = (u + 0x7fffu + ((u >> 16) & 1u)) >> 16;
    return (unsigned short)u;
}
__device__ __forceinline__ uint32 pack_f16(float a, float b) {
    __half ha = __float2half_rn(a), hb = __float2half_rn(b);
    return (uint32)__half_as_ushort(ha) | ((uint32)__half_as_ushort(hb) << 16);
}
__device__ __forceinline__ float fast_tanh(float x) {
    x = fminf(fmaxf(x, -15.f), 15.f);
    float e = __expf(2.f * x);
    return __fdividef(e - 1.f, e + 1.f);
}
__device__ __forceinline__ float fast_sigmoid(float x) {
    return __fdividef(1.f, 1.f + __expf(-x));
}
// 2-way f16 dot with f32 accumulate (v_dot2_f32_f16), guarded fallback
__device__ __forceinline__ float fdot2(uint32 w, uint32 v, float acc) {
#if __has_builtin(__builtin_amdgcn_fdot2)
    return __builtin_amdgcn_fdot2(__builtin_bit_cast(hf2, w), __builtin_bit_cast(hf2, v), acc, false);
#else
    __half2 wh = __builtin_bit_cast(__half2, w), vh = __builtin_bit_cast(__half2, v);
    float2 wf = __half22float2(wh), vf = __half22float2(vh);
    return fmaf(wf.y, vf.y, fmaf(wf.x, vf.x, acc));
#endif
}

// LDS flag ops (workgroup scope: ds ops only, no cache maintenance)
__device__ __forceinline__ void spin_ge(uint32* p, uint32 tgt) {
    int guard = 0;
    while (__hip_atomic_load(p, __ATOMIC_ACQUIRE, __HIP_MEMORY_SCOPE_WORKGROUP) < tgt) {
        __builtin_amdgcn_s_sleep(1);
        if (++guard > (1 << 22)) break;  // safety valve: wrong answer beats a hang
    }
}
__device__ __forceinline__ void st_flag(uint32* p, uint32 v) {
    __hip_atomic_store(p, v, __ATOMIC_RELEASE, __HIP_MEMORY_SCOPE_WORKGROUP);
}
__device__ __forceinline__ void add_flag(uint32* p, uint32 v) {
    __hip_atomic_fetch_add(p, v, __ATOMIC_RELEASE, __HIP_MEMORY_SCOPE_WORKGROUP);
}

// ---------- prep 1: f16-convert + re-layout weights ----------
// We2: uint4[64][128]; [jq][s] = 4 half2: (We[s][8jq+2p], We[s][8jq+2p+1]), p=0..3
//      (hs reduction dim j in [0,512) = [h(256)|c(256)])
// Wc2: uint4[192][256]; [np][q] = 4 half2: gate g=4q+p gets (W[g][2np], W[g][2np+1])
//      where K-dim n in [0,384) = [xw(128)|h(256)]:
//      W[g][n] = (n<128) ? W_ih[g][n] : W_hh[g][n-128]
__global__ void prep_weights(const float* __restrict__ We, const float* __restrict__ W_ih,
                             const float* __restrict__ W_hh, uint32* __restrict__ We2,
                             uint32* __restrict__ Wc2) {
    int idx = blockIdx.x * 256 + threadIdx.x;
    if (idx < 32768) {
        int p = idx & 3, s = (idx >> 2) & 127, jq = idx >> 9;
        int j = 8 * jq + 2 * p;
        We2[idx] = pack_f16(We[s * 512 + j], We[s * 512 + j + 1]);
    } else if (idx < 229376) {
        int i2 = idx - 32768;
        int p = i2 & 3, q = (i2 >> 2) & 255, np = i2 >> 10;
        int g = 4 * q + p;
        int n0 = 2 * np, n1 = 2 * np + 1;
        float w0, w1;
        if (n0 < 128) {
            w0 = W_ih[g * 128 + n0];
            w1 = W_ih[g * 128 + n1];
        } else {
            w0 = W_hh[g * 256 + (n0 - 128)];
            w1 = W_hh[g * 256 + (n1 - 128)];
        }
        Wc2[i2] = pack_f16(w0, w1);
    }
}

// ---------- prep 2: Ux[b,s,n] = sum_t x[b,t,n] * Ue[s,t]  (bf16 out) ----------
__global__ void ux_kernel(const float* __restrict__ x, const float* __restrict__ Ue,
                          unsigned short* __restrict__ Uxg) {
    int b = blockIdx.x >> 1, h = blockIdx.x & 1;
    int n = threadIdx.x & 127, sg = threadIdx.x >> 7;
    int s0 = h * 64 + sg * 16;
    float acc[16];
#pragma unroll
    for (int k = 0; k < 16; ++k) acc[k] = 0.f;
    for (int t0 = 0; t0 < 128; t0 += 16) {
        float xv[16];
#pragma unroll
        for (int tt = 0; tt < 16; ++tt) xv[tt] = x[(b * 128 + t0 + tt) * 128 + n];
#pragma unroll
        for (int k = 0; k < 16; ++k) {
            const float4* uep = (const float4*)(Ue + (s0 + k) * 128 + t0);
            float4 u0 = uep[0], u1 = uep[1], u2 = uep[2], u3 = uep[3];
            acc[k] += xv[0] * u0.x + xv[1] * u0.y + xv[2] * u0.z + xv[3] * u0.w
                    + xv[4] * u1.x + xv[5] * u1.y + xv[6] * u1.z + xv[7] * u1.w
                    + xv[8] * u2.x + xv[9] * u2.y + xv[10] * u2.z + xv[11] * u2.w
                    + xv[12] * u3.x + xv[13] * u3.y + xv[14] * u3.z + xv[15] * u3.w;
        }
    }
#pragma unroll
    for (int k = 0; k < 16; ++k)
        Uxg[b * 16384 + (s0 + k) * 128 + n] = f2bf(acc[k]);
}

// ---------- main: 128 blocks, wave-specialized, barrier-free step loop ----------
// A-waves (tid<768): 6 groups of 128 threads; thread owns gate-octet ol (gates
//   8ol..8ol+7). Groups 0-3: h-part K-chunks (start on h_flag). Groups 4,5:
//   attention ph1 (WeQ stream) -> cnt1, then xw-part K-chunks (on xw_flag).
// B-waves (tid>=768, 256 thr): cnt1 -> web (per-wave regs) -> ph2 tanh -> cnt2;
//   wave12: ph3 softmax -> xw_flag; all: cnt4 -> ph5 gate-reduce+pointwise ->
//   cnt5; wave12: h_flag.
__global__ __launch_bounds__(NT, 4)
void encoder_kernel(const float* __restrict__ x, const float* __restrict__ v_e,
                    const float* __restrict__ b_ih, const float* __restrict__ b_hh,
                    const unsigned short* __restrict__ Uxg, const uint4* __restrict__ We2q,
                    const uint4* __restrict__ Wc2q, float* __restrict__ out) {
    __shared__ __align__(16) unsigned short Ux_s[16384];  // 32 KB [s][n] bf16
    __shared__ __align__(16) float part4[6144];           // 24 KB [grp][1024 gates]
    __shared__ float part1[256];                          // [jg][s]
    __shared__ float part2[256];                          // [sg][n]
    __shared__ uint32 vh_s[192];    // half2 pairs of v=[xw(0..64)|h(64..192)]
    __shared__ uint32 hsh_s[256];   // half2 pairs of hs=[h(0..128)|c(128..256)]
    __shared__ float c_s[256];      // f32 c state
    __shared__ __align__(16) float bias_s[1024];
    __shared__ float ve_s[128];
    __shared__ uint32 h_flag, xw_flag, cnt1, cnt2, cnt4, cnt5;
    __shared__ float pad_force[4096];  // LDS pad -> 1 block/CU

    const int tid = threadIdx.x;
    const int b = blockIdx.x;

    {   // load this batch's Ux tile (coalesced)
        const uint4* src = (const uint4*)(Uxg + b * 16384);
        uint4* dst = (uint4*)Ux_s;
        for (int i = tid; i < 2048; i += NT) dst[i] = src[i];
    }
    bias_s[tid] = b_ih[tid] + b_hh[tid];
    if (tid < 128) ve_s[tid] = v_e[tid];
    if (tid < 192) vh_s[tid] = 0u;
    if (tid < 256) { hsh_s[tid] = 0u; c_s[tid] = 0.f; }
    if (tid == 0) { h_flag = 0; xw_flag = 0; cnt1 = 0; cnt2 = 0; cnt4 = 0; cnt5 = 0; }
    __syncthreads();  // the only barrier; all threads reach it

    if (tid < 768) {
        // ================= A-group =================
        const int ol = tid & 127, g = tid >> 7;
        const uint4* wc = Wc2q + 2 * ol;
        for (int t = 0; t < 128; ++t) {
            float a0 = 0.f, a1 = 0.f, a2 = 0.f, a3 = 0.f;
            float a4 = 0.f, a5 = 0.f, a6 = 0.f, a7 = 0.f;
            spin_ge(&h_flag, (uint32)t);
            if (g < 4) {
                // h-part: np in [64+32g, 64+32g+32)
                const int np0 = 64 + g * 32;
#pragma unroll 8
                for (int i = 0; i < 32; ++i) {
                    int np = np0 + i;
                    uint32 vp = vh_s[np];
                    uint4 w0 = wc[np * 256];
                    uint4 w1 = wc[np * 256 + 1];
                    a0 = fdot2(w0.x, vp, a0); a1 = fdot2(w0.y, vp, a1);
                    a2 = fdot2(w0.z, vp, a2); a3 = fdot2(w0.w, vp, a3);
                    a4 = fdot2(w1.x, vp, a4); a5 = fdot2(w1.y, vp, a5);
                    a6 = fdot2(w1.z, vp, a6); a7 = fdot2(w1.w, vp, a7);
                }
            } else {
                // ph1: web partial over hs-chunk jg
                const int s = ol, jg = g - 4;
                float acc = 0.f;
#pragma unroll 8
                for (int jq = jg * 32; jq < jg * 32 + 32; ++jq) {
                    uint4 w = We2q[jq * 128 + s];
                    acc = fdot2(w.x, hsh_s[4 * jq + 0], acc);
                    acc = fdot2(w.y, hsh_s[4 * jq + 1], acc);
                    acc = fdot2(w.z, hsh_s[4 * jq + 2], acc);
                    acc = fdot2(w.w, hsh_s[4 * jq + 3], acc);
                }
                part1[jg * 128 + s] = acc;
                if ((tid & 63) == 0) add_flag(&cnt1, 1);
                // xw-part: np in [32(g-4), 32(g-4)+32)
                spin_ge(&xw_flag, (uint32)(t + 1));
                const int np0 = jg * 32;
#pragma unroll 8
                for (int i = 0; i < 32; ++i) {
                    int np = np0 + i;
                    uint32 vp = vh_s[np];
                    uint4 w0 = wc[np * 256];
                    uint4 w1 = wc[np * 256 + 1];
                    a0 = fdot2(w0.x, vp, a0); a1 = fdot2(w0.y, vp, a1);
                    a2 = fdot2(w0.z, vp, a2); a3 = fdot2(w0.w, vp, a3);
                    a4 = fdot2(w1.x, vp, a4); a5 = fdot2(w1.y, vp, a5);
                    a6 = fdot2(w1.z, vp, a6); a7 = fdot2(w1.w, vp, a7);
                }
            }
            float4* p4 = (float4*)&part4[g * 1024 + 8 * ol];
            p4[0] = make_float4(a0, a1, a2, a3);
            p4[1] = make_float4(a4, a5, a6, a7);
            if ((tid & 63) == 0) add_flag(&cnt4, 1);
        }
    } else {
        // ================= B-group =================
        const int bt = tid - 768, l = tid & 63;
        const int n = bt & 127, sg = bt >> 7;
        for (int t = 0; t < 128; ++t) {
            float2 xt2;
            if (bt < 64) xt2 = *(const float2*)(x + (b * 128 + t) * 128 + 2 * l);
            spin_ge(&cnt1, (uint32)(4 * (t + 1)));
            // per-wave redundant web (no extra sync): lane l holds web[l], web[64+l]
            float web_lo = part1[l] + part1[128 + l];
            float web_hi = part1[64 + l] + part1[192 + l];
            float wsel = sg ? web_hi : web_lo;
            // ph2: scores partial over s-chunk sg
            float acc = 0.f;
#pragma unroll 8
            for (int k = 0; k < 64; ++k) {
                float wv = __shfl(wsel, k);
                float a = wv + bfu(Ux_s[(sg * 64 + k) * 128 + n]);
                acc += ve_s[sg * 64 + k] * fast_tanh(a);
            }
            part2[sg * 128 + n] = acc;
            if (l == 0) add_flag(&cnt2, 1);
            if (bt < 64) {
                // ph3: softmax + xw (wave 12 only); lane l owns n=2l, 2l+1
                spin_ge(&cnt2, (uint32)(4 * (t + 1)));
                float v0 = part2[2 * l] + part2[128 + 2 * l];
                float v1 = part2[2 * l + 1] + part2[129 + 2 * l];
                float m = fmaxf(v0, v1);
#pragma unroll
                for (int off = 32; off > 0; off >>= 1) m = fmaxf(m, __shfl_xor(m, off));
                float e0 = __expf(v0 - m), e1 = __expf(v1 - m);
                float ssum = e0 + e1;
#pragma unroll
                for (int off = 32; off > 0; off >>= 1) ssum += __shfl_xor(ssum, off);
                float inv = __fdividef(1.f, ssum);
                vh_s[l] = pack_f16(xt2.x * e0 * inv, xt2.y * e1 * inv);
                if (bt == 0) st_flag(&xw_flag, (uint32)(t + 1));
            }
            // ph5: gate reduce + LSTM pointwise (all 4 B-waves; thread = h-unit j)
            spin_ge(&cnt4, (uint32)(12 * (t + 1)));
            const int j = bt;
            float gi = bias_s[j], gf = bias_s[256 + j];
            float gg = bias_s[512 + j], go = bias_s[768 + j];
#pragma unroll
            for (int gr = 0; gr < 6; ++gr) {
                const float* pp = part4 + gr * 1024;
                gi += pp[j]; gf += pp[256 + j];
                gg += pp[512 + j]; go += pp[768 + j];
            }
            float c = c_s[j];
            float c2 = fast_sigmoid(gf) * c + fast_sigmoid(gi) * fast_tanh(gg);
            float h2v = fast_sigmoid(go) * fast_tanh(c2);
            c_s[j] = c2;
            out[(t * 128 + b) * 256 + j] = h2v;
            float hn = __shfl_xor(h2v, 1);
            float cn = __shfl_xor(c2, 1);
            if (!(j & 1)) {
                uint32 hp = pack_f16(h2v, hn);
                vh_s[64 + (j >> 1)] = hp;       // v h-pairs for gate GEMV
                hsh_s[j >> 1] = hp;             // hs h-pairs for ph1
                hsh_s[128 + (j >> 1)] = pack_f16(c2, cn);  // hs c-pairs
            }
            if (l == 0) add_flag(&cnt5, 1);
            if (bt == 0) {
                spin_ge(&cnt5, (uint32)(4 * (t + 1)));
                st_flag(&h_flag, (uint32)(t + 1));
            }
        }
        // keep pad_force alive (never true at runtime)
        if (__hip_atomic_load(&h_flag, __ATOMIC_RELAXED, __HIP_MEMORY_SCOPE_WORKGROUP) == 0xffffffffu)
            pad_force[tid & 4095] = 0.f;
    }
}

extern "C" void kernel_launch(void* const* d_in, const int* in_sizes, int n_in,
                              void* d_out, int out_size, void* d_ws, size_t ws_size,
                              hipStream_t stream) {
    const float* x    = (const float*)d_in[0];
    const float* We   = (const float*)d_in[1];
    const float* Ue   = (const float*)d_in[2];
    const float* v_e  = (const float*)d_in[3];
    const float* W_ih = (const float*)d_in[4];
    const float* W_hh = (const float*)d_in[5];
    const float* b_ih = (const float*)d_in[6];
    const float* b_hh = (const float*)d_in[7];
    float* out = (float*)d_out;

    char* w = (char*)d_ws;
    unsigned short* Uxg = (unsigned short*)w;      // 4 MB
    uint32* We2 = (uint32*)(w + 4194304);          // 128 KB
    uint32* Wc2 = (uint32*)(w + 4325376);          // 768 KB

    prep_weights<<<896, 256, 0, stream>>>(We, W_ih, W_hh, We2, Wc2);
    ux_kernel<<<256, 512, 0, stream>>>(x, Ue, Uxg);
    encoder_kernel<<<128, NT, 0, stream>>>(x, v_e, b_ih, b_hh, Uxg,
                                           (const uint4*)We2, (const uint4*)Wc2, out);
}